// Round 1
// baseline (3605.499 us; speedup 1.0000x reference)
//
#include <hip/hip_runtime.h>
#include <hip/hip_cooperative_groups.h>

namespace cg = cooperative_groups;

// Problem dims (fixed by reference)
#define B_  256
#define L_  64
#define DI_ 2048
#define T_  32
#define DT_ 512
#define U_  512
#define A_  512
#define N3U 1536   // 3*U

typedef short short8 __attribute__((ext_vector_type(8)));   // 8 bf16 = 4 VGPRs
typedef float floatx4 __attribute__((ext_vector_type(4)));  // mfma acc
typedef unsigned short ushort4v __attribute__((ext_vector_type(4)));

// fp32 -> bf16 round-to-nearest-even
__device__ __forceinline__ unsigned short f2bf(float f) {
  unsigned int u = __float_as_uint(f);
  u += 0x7fffu + ((u >> 16) & 1u);
  return (unsigned short)(u >> 16);
}
__device__ __forceinline__ float bf2f(unsigned short s) {
  return __uint_as_float(((unsigned int)s) << 16);
}
__device__ __forceinline__ float fast_tanh(float x) {
  x = fminf(fmaxf(x, -15.f), 15.f);
  float e = __expf(2.f * x);
  return (e - 1.f) / (e + 1.f);
}

// ---------------------------------------------------------------------------
// MFMA GEMM with fused A-conversion:
//   C[M,N] = A[M,K](fp32) @ Bt[N,K](bf16)^T (+bias)
// out_mode: 0 = fp32 row-major, 1 = bf16 row-major,
//           2 = bf16 in imgW8 layout [b][l>>3][col][l&7] (requires N==1536,
//               M = batch*64; acc's 4 regs = 4 consecutive l's -> 8B store).
// 128x128 tile, BK=32, 256 threads = 4 waves, each wave 64x64 sub-tile.
// ---------------------------------------------------------------------------
__global__ __launch_bounds__(256) void gemm_a32_bt16_mfma(
    const float* __restrict__ A, const unsigned short* __restrict__ Bt,
    const float* __restrict__ bias, void* __restrict__ Cout,
    int M, int N, int K, int out_mode) {
  __shared__ unsigned short As[128][40];
  __shared__ unsigned short Bs[128][40];
  const int tid  = threadIdx.x;
  const int wave = tid >> 6;
  const int lane = tid & 63;
  const int quad = lane >> 4;
  const int lr   = lane & 15;
  const int wrow = (wave >> 1) * 64;
  const int wcol = (wave & 1) * 64;
  const size_t bm = (size_t)blockIdx.y * 128;
  const size_t bn = (size_t)blockIdx.x * 128;

  const int sr = tid >> 2;          // staging row 0..63
  const int sc = (tid & 3) * 8;     // staging col (ushorts) 0,8,16,24

  floatx4 acc[4][4] = {};

  for (int k0 = 0; k0 < K; k0 += 32) {
#pragma unroll
    for (int it = 0; it < 2; ++it) {
      const int row = sr + it * 64;
      const float* ap = A + (bm + row) * (size_t)K + k0 + sc;
      float4 a0 = *(const float4*)(ap);
      float4 a1 = *(const float4*)(ap + 4);
      short8 pk;
      pk[0] = (short)f2bf(a0.x); pk[1] = (short)f2bf(a0.y);
      pk[2] = (short)f2bf(a0.z); pk[3] = (short)f2bf(a0.w);
      pk[4] = (short)f2bf(a1.x); pk[5] = (short)f2bf(a1.y);
      pk[6] = (short)f2bf(a1.z); pk[7] = (short)f2bf(a1.w);
      *(short8*)&As[row][sc] = pk;
      *(float4*)&Bs[row][sc] = *(const float4*)(Bt + (bn + row) * (size_t)K + k0 + sc);
    }
    __syncthreads();
    short8 af[4], bf[4];
#pragma unroll
    for (int mi = 0; mi < 4; ++mi) af[mi] = *(const short8*)&As[wrow + mi * 16 + lr][quad * 8];
#pragma unroll
    for (int ni = 0; ni < 4; ++ni) bf[ni] = *(const short8*)&Bs[wcol + ni * 16 + lr][quad * 8];
#pragma unroll
    for (int mi = 0; mi < 4; ++mi)
#pragma unroll
      for (int ni = 0; ni < 4; ++ni)
        acc[mi][ni] = __builtin_amdgcn_mfma_f32_16x16x32_bf16(af[mi], bf[ni], acc[mi][ni], 0, 0, 0);
    __syncthreads();
  }

  float* outf = (float*)Cout;
  unsigned short* outb = (unsigned short*)Cout;
#pragma unroll
  for (int mi = 0; mi < 4; ++mi) {
#pragma unroll
    for (int ni = 0; ni < 4; ++ni) {
      const size_t row0 = bm + wrow + mi * 16 + quad * 4;
      const size_t col  = bn + wcol + ni * 16 + lr;
      const float bsum = bias ? bias[col] : 0.f;
      if (out_mode == 2) {
        // imgW8 layout: [b][j][col][i], b=row/64, j=(row%64)>>3, i=(row%64)&7
        const size_t bidx = row0 >> 6;
        const int l0 = (int)(row0 & 63);
        const int j = l0 >> 3, i0 = l0 & 7;      // i0 in {0,4}: 4 regs contiguous
        ushort4v pk;
#pragma unroll
        for (int reg = 0; reg < 4; ++reg) pk[reg] = f2bf(acc[mi][ni][reg] + bsum);
        *(ushort4v*)(outb + (((bidx * 8 + j) * 1536 + col) << 3) + i0) = pk;
      } else {
#pragma unroll
        for (int reg = 0; reg < 4; ++reg) {
          const float v = acc[mi][ni][reg] + bsum;
          if (out_mode == 1) outb[(row0 + reg) * (size_t)N + col] = f2bf(v);
          else               outf[(row0 + reg) * (size_t)N + col] = v;
        }
      }
    }
  }
}

// ---------------------------------------------------------------------------
// small helpers
// ---------------------------------------------------------------------------
// in[K,N] fp32 -> out[N,K] bf16 (tiled transpose). K%32==0, N%32==0.
__global__ __launch_bounds__(256) void transpose_f32_bf16(
    const float* __restrict__ in, unsigned short* __restrict__ outp, int K, int N) {
  __shared__ unsigned short tile[32][33];
  const int tid = threadIdx.x;
  const int tx = tid & 31, ty = tid >> 5;  // ty 0..7
  const int k0 = blockIdx.y * 32, n0 = blockIdx.x * 32;
#pragma unroll
  for (int i = 0; i < 4; ++i) {
    const int kk = ty + i * 8;
    tile[tx][kk] = f2bf(in[(size_t)(k0 + kk) * N + n0 + tx]);
  }
  __syncthreads();
#pragma unroll
  for (int i = 0; i < 4; ++i) {
    const int nn = ty + i * 8;
    outp[(size_t)(n0 + nn) * K + k0 + tx] = tile[nn][tx];
  }
}

// bcat[2048] = [att_hid_bias | rec_bias]
__global__ void build_bcat(const float* __restrict__ ahb,
                           const float* __restrict__ rb,
                           float* __restrict__ bcat) {
  int i = blockIdx.x * 256 + threadIdx.x;
  if (i < A_) bcat[i] = ahb[i];
  else if (i < A_ + N3U) bcat[i] = rb[i - A_];
}

// ---------------------------------------------------------------------------
// Persistent cooperative recurrence: all 32 steps in one launch.
// 256 blocks x 512 threads (1 block/CU).
// Per step:
//   phase 1: hm = h @ Wcat + bcat  (MFMA, 32x64 tile per block = 256 blocks)
//   grid.sync()
//   phase 2: block b = attention + GRU for batch b (same math as before,
//            phase B reads imgW8 with coalesced 16B loads)
//   grid.sync()
// ---------------------------------------------------------------------------
__global__ __launch_bounds__(512) void recurrence(
    const unsigned short* __restrict__ img_proj,   // [B,L,A] bf16
    const unsigned short* __restrict__ imgW8,      // [B][8][3U][8] bf16
    const float* __restrict__ text_proj,           // [B,T,3U] fp32
    const unsigned short* __restrict__ wcatT,      // [2048,512] bf16
    const float* __restrict__ bcat,                // [2048]
    const float* __restrict__ vk,                  // [A]
    float* __restrict__ h,                         // [B,U]
    float* __restrict__ hm,                        // [B,2048]
    float* __restrict__ out) {                     // [B,T,U]
  cg::grid_group grid = cg::this_grid();
  const int tid  = threadIdx.x;
  const int bid  = blockIdx.x;
  const int wave = tid >> 6;
  const int lane = tid & 63;
  const int quad = lane >> 4;
  const int lr   = lane & 15;
  const int b    = bid;

  __shared__ unsigned short As[32][520];   // h tile bf16, pad 8 -> 2-way-free
  __shared__ float sc[L_];
  __shared__ float aw[L_];

  // init h = 0 (grid covers exactly B*U threads)
  h[(size_t)bid * U_ + tid] = 0.f;

  // hoisted: per-lane slice of v (a = lane*8 + j)
  float vvv[8];
  {
    float4 v0 = *(const float4*)(vk + lane * 8);
    float4 v1 = *(const float4*)(vk + lane * 8 + 4);
    vvv[0]=v0.x; vvv[1]=v0.y; vvv[2]=v0.z; vvv[3]=v0.w;
    vvv[4]=v1.x; vvv[5]=v1.y; vvv[6]=v1.z; vvv[7]=v1.w;
  }

  // phase-1 tile constants: 8 m-tiles (32 rows) x 32 n-tiles (64 cols)
  const int mt   = bid & 7;
  const int nt   = bid >> 3;
  const int mrow = (wave >> 2) * 16;               // 0 or 16
  const int ncol = nt * 64 + (wave & 3) * 16;      // global col of this frag

  grid.sync();

  for (int t = 0; t < T_; ++t) {
    // ---- phase 1: hm tile [mt*32 .. +32) x [nt*64 .. +64) ----
    {
      const int r  = tid >> 4;                 // 0..31
      const int c0 = (tid & 15) << 5;          // 0..480 step 32
      const float* hp = h + (size_t)(mt * 32 + r) * U_ + c0;
#pragma unroll
      for (int i = 0; i < 4; ++i) {
        float4 x0 = *(const float4*)(hp + i * 8);
        float4 x1 = *(const float4*)(hp + i * 8 + 4);
        short8 pk;
        pk[0] = (short)f2bf(x0.x); pk[1] = (short)f2bf(x0.y);
        pk[2] = (short)f2bf(x0.z); pk[3] = (short)f2bf(x0.w);
        pk[4] = (short)f2bf(x1.x); pk[5] = (short)f2bf(x1.y);
        pk[6] = (short)f2bf(x1.z); pk[7] = (short)f2bf(x1.w);
        *(short8*)&As[r][c0 + i * 8] = pk;
      }
      __syncthreads();
      floatx4 acc = {};
#pragma unroll
      for (int k0 = 0; k0 < U_; k0 += 32) {
        short8 af  = *(const short8*)&As[mrow + lr][k0 + quad * 8];
        short8 bfr = *(const short8*)(wcatT + (size_t)(ncol + lr) * U_ + k0 + quad * 8);
        acc = __builtin_amdgcn_mfma_f32_16x16x32_bf16(af, bfr, acc, 0, 0, 0);
      }
      const int col  = ncol + lr;
      const float bs = bcat[col];
      const int orow = mt * 32 + mrow + quad * 4;
#pragma unroll
      for (int reg = 0; reg < 4; ++reg)
        hm[(size_t)(orow + reg) * 2048 + col] = acc[reg] + bs;
    }
    grid.sync();

    // ---- phase 2: attention + GRU for batch b ----
    const float* hpg = hm + (size_t)b * 2048;     // hproj = cols [0,512)
    float hpv[8];
    {
      float4 h0 = *(const float4*)(hpg + lane * 8);
      float4 h1 = *(const float4*)(hpg + lane * 8 + 4);
      hpv[0]=h0.x; hpv[1]=h0.y; hpv[2]=h0.z; hpv[3]=h0.w;
      hpv[4]=h1.x; hpv[5]=h1.y; hpv[6]=h1.z; hpv[7]=h1.w;
    }
    // scores: wave w handles l = w, w+8, ...
#pragma unroll
    for (int i = 0; i < 8; ++i) {
      const int l = wave + i * 8;
      const unsigned short* ip = img_proj + ((size_t)b * L_ + l) * A_ + lane * 8;
      short8 v8 = *(const short8*)ip;
      float s = 0.f;
#pragma unroll
      for (int j = 0; j < 8; ++j)
        s += fast_tanh(bf2f((unsigned short)v8[j]) + hpv[j]) * vvv[j];
#pragma unroll
      for (int off = 32; off; off >>= 1) s += __shfl_down(s, off);
      if (lane == 0) sc[l] = s;
    }
    __syncthreads();
    // softmax over 64 regions
    if (tid < 64) {
      float x = sc[tid];
      float m = x;
#pragma unroll
      for (int off = 32; off; off >>= 1) m = fmaxf(m, __shfl_xor(m, off));
      float e = __expf(x - m);
      float ssum = e;
#pragma unroll
      for (int off = 32; off; off >>= 1) ssum += __shfl_xor(ssum, off);
      aw[tid] = e / ssum;
    }
    __syncthreads();

    // combine + gates: thread u owns gate triple (u, 512+u, 1024+u)
    const int u = tid;
    const unsigned short* iwb = imgW8 + (size_t)b * 8 * (N3U * 8) + (size_t)u * 8;
    float s0 = 0.f, s1 = 0.f, s2 = 0.f;
#pragma unroll
    for (int j = 0; j < 8; ++j) {
      const unsigned short* pj = iwb + (size_t)j * (N3U * 8);
      short8 v0 = *(const short8*)(pj);
      short8 v1 = *(const short8*)(pj + 512 * 8);
      short8 v2 = *(const short8*)(pj + 1024 * 8);
#pragma unroll
      for (int i = 0; i < 8; ++i) {
        const float a = aw[j * 8 + i];      // l = j*8+i: same order as before
        s0 += a * bf2f((unsigned short)v0[i]);
        s1 += a * bf2f((unsigned short)v1[i]);
        s2 += a * bf2f((unsigned short)v2[i]);
      }
    }
    const float* tp  = text_proj + ((size_t)b * T_ + t) * N3U;
    const float* mib = hpg + 512;                 // mi = cols [512,2048)
    const float xz = s0 + tp[u]        + mib[u];
    const float xr = s1 + tp[512 + u]  + mib[512 + u];
    const float xh = s2 + tp[1024 + u];
    const float rh = mib[1024 + u];
    const float z  = 1.f / (1.f + __expf(-xz));
    const float r  = 1.f / (1.f + __expf(-xr));
    const float hh = fast_tanh(xh + r * rh);
    const float hn = z * h[(size_t)b * U_ + u] + (1.f - z) * hh;
    h[(size_t)b * U_ + u] = hn;
    out[((size_t)b * T_ + t) * U_ + u] = hn;
    grid.sync();
  }
}

// ---------------------------------------------------------------------------
// launch
// ---------------------------------------------------------------------------
extern "C" void kernel_launch(void* const* d_in, const int* in_sizes, int n_in,
                              void* d_out, int out_size, void* d_ws, size_t ws_size,
                              hipStream_t stream) {
  const float* img        = (const float*)d_in[0];   // [B,L,DI]
  const float* text       = (const float*)d_in[1];   // [B,T,DT]
  const float* kern       = (const float*)d_in[2];   // [DT+DI, 3U]
  const float* input_bias = (const float*)d_in[3];   // [3U]
  const float* rec_kern   = (const float*)d_in[4];   // [U,3U]
  const float* rec_bias   = (const float*)d_in[5];   // [3U]
  const float* att_img_k  = (const float*)d_in[6];   // [DI,A]
  const float* att_img_b  = (const float*)d_in[7];   // [A]
  const float* att_hid_k  = (const float*)d_in[8];   // [U,A]
  const float* att_hid_b  = (const float*)d_in[9];   // [A]
  const float* att_v_k    = (const float*)d_in[10];  // [A,1]
  // d_in[11] = att_v_bias — cancels in softmax.
  float* out = (float*)d_out;

  // workspace layout (bytes, 256-aligned). NO ALIASING. ~132 MB total.
  char* ws = (char*)d_ws;
  size_t off = 0;
  auto alloc = [&](size_t bytes) { char* p = ws + off; off += (bytes + 255) & ~(size_t)255; return p; };
  unsigned short* img_proj = (unsigned short*)alloc((size_t)B_*L_*A_*2);   // 16.8 MB bf16
  unsigned short* imgW8    = (unsigned short*)alloc((size_t)B_*L_*N3U*2);  // 50.3 MB bf16 [b][j][n][i]
  float*          text_proj= (float*)         alloc((size_t)B_*T_*N3U*4);  // 50.3 MB fp32
  unsigned short* wt1      = (unsigned short*)alloc((size_t)A_*DI_*2);     // att_img_k^T
  unsigned short* wt2      = (unsigned short*)alloc((size_t)N3U*DI_*2);    // kern[DT:]^T
  unsigned short* wt3      = (unsigned short*)alloc((size_t)N3U*DT_*2);    // kern[:DT]^T
  unsigned short* wcatT    = (unsigned short*)alloc((size_t)2048*U_*2);    // [ahk|rk]^T bf16 [2048,512]
  float*          bcat     = (float*)         alloc(2048*4);
  float*          h        = (float*)         alloc((size_t)B_*U_*4);
  float*          hm       = (float*)         alloc((size_t)B_*2048*4);

  dim3 blk(256);

  // one-time weight transposes (fp32 -> bf16^T)
  transpose_f32_bf16<<<dim3(A_/32, DI_/32), blk, 0, stream>>>(att_img_k, wt1, DI_, A_);
  transpose_f32_bf16<<<dim3(N3U/32, DI_/32), blk, 0, stream>>>(kern + (size_t)DT_*N3U, wt2, DI_, N3U);
  transpose_f32_bf16<<<dim3(N3U/32, DT_/32), blk, 0, stream>>>(kern, wt3, DT_, N3U);
  // wcatT rows [0,512) = att_hid_k^T ; rows [512,2048) = rec_kern^T
  transpose_f32_bf16<<<dim3(A_/32, U_/32), blk, 0, stream>>>(att_hid_k, wcatT, U_, A_);
  transpose_f32_bf16<<<dim3(N3U/32, U_/32), blk, 0, stream>>>(rec_kern, wcatT + (size_t)A_*U_, U_, N3U);
  build_bcat<<<dim3(8), blk, 0, stream>>>(att_hid_b, rec_bias, bcat);

  // big GEMMs on MFMA (A operand converted fp32->bf16 during staging)
  gemm_a32_bt16_mfma<<<dim3(A_/128, (B_*L_)/128), blk, 0, stream>>>(
      img, wt1, att_img_b, img_proj, B_*L_, A_, DI_, 1);
  gemm_a32_bt16_mfma<<<dim3(N3U/128, (B_*L_)/128), blk, 0, stream>>>(
      img, wt2, nullptr, imgW8, B_*L_, N3U, DI_, 2);     // direct imgW8 layout
  gemm_a32_bt16_mfma<<<dim3(N3U/128, (B_*T_)/128), blk, 0, stream>>>(
      text, wt3, input_bias, text_proj, B_*T_, N3U, DT_, 0);

  // entire 32-step recurrence: one cooperative launch, grid syncs inside
  void* kargs[] = {
    (void*)&img_proj, (void*)&imgW8, (void*)&text_proj, (void*)&wcatT,
    (void*)&bcat, (void*)&att_v_k, (void*)&h, (void*)&hm, (void*)&out
  };
  hipLaunchCooperativeKernel((const void*)recurrence, dim3(256), dim3(512),
                             kargs, 0, stream);
}

// Round 2
// 2563.116 us; speedup vs baseline: 1.4067x; 1.4067x over previous
//
#include <hip/hip_runtime.h>

// Problem dims (fixed by reference)
#define B_  256
#define L_  64
#define DI_ 2048
#define T_  32
#define DT_ 512
#define U_  512
#define A_  512
#define N3U 1536   // 3*U

typedef short short8 __attribute__((ext_vector_type(8)));   // 8 bf16 = 4 VGPRs
typedef float floatx4 __attribute__((ext_vector_type(4)));  // mfma acc
typedef unsigned short ushort4v __attribute__((ext_vector_type(4)));

// fp32 -> bf16 round-to-nearest-even
__device__ __forceinline__ unsigned short f2bf(float f) {
  unsigned int u = __float_as_uint(f);
  u += 0x7fffu + ((u >> 16) & 1u);
  return (unsigned short)(u >> 16);
}
__device__ __forceinline__ float bf2f(unsigned short s) {
  return __uint_as_float(((unsigned int)s) << 16);
}
__device__ __forceinline__ float fast_tanh(float x) {
  x = fminf(fmaxf(x, -15.f), 15.f);
  float e = __expf(2.f * x);
  return (e - 1.f) / (e + 1.f);
}

// ---------------------------------------------------------------------------
// MFMA GEMM with fused A-conversion:
//   C[M,N] = A[M,K](fp32) @ Bt[N,K](bf16)^T (+bias)
// out_mode: 0 = fp32 row-major, 1 = bf16 row-major,
//           2 = bf16 in imgW8 layout [b][l>>3][col][l&7] (requires N==1536,
//               M = batch*64; acc's 4 regs = 4 consecutive l's -> 8B store).
// 128x128 tile, BK=32, 256 threads = 4 waves, each wave 64x64 sub-tile.
// ---------------------------------------------------------------------------
__global__ __launch_bounds__(256) void gemm_a32_bt16_mfma(
    const float* __restrict__ A, const unsigned short* __restrict__ Bt,
    const float* __restrict__ bias, void* __restrict__ Cout,
    int M, int N, int K, int out_mode) {
  __shared__ unsigned short As[128][40];
  __shared__ unsigned short Bs[128][40];
  const int tid  = threadIdx.x;
  const int wave = tid >> 6;
  const int lane = tid & 63;
  const int quad = lane >> 4;
  const int lr   = lane & 15;
  const int wrow = (wave >> 1) * 64;
  const int wcol = (wave & 1) * 64;
  const size_t bm = (size_t)blockIdx.y * 128;
  const size_t bn = (size_t)blockIdx.x * 128;

  const int sr = tid >> 2;          // staging row 0..63
  const int sc = (tid & 3) * 8;     // staging col (ushorts) 0,8,16,24

  floatx4 acc[4][4] = {};

  for (int k0 = 0; k0 < K; k0 += 32) {
#pragma unroll
    for (int it = 0; it < 2; ++it) {
      const int row = sr + it * 64;
      const float* ap = A + (bm + row) * (size_t)K + k0 + sc;
      float4 a0 = *(const float4*)(ap);
      float4 a1 = *(const float4*)(ap + 4);
      short8 pk;
      pk[0] = (short)f2bf(a0.x); pk[1] = (short)f2bf(a0.y);
      pk[2] = (short)f2bf(a0.z); pk[3] = (short)f2bf(a0.w);
      pk[4] = (short)f2bf(a1.x); pk[5] = (short)f2bf(a1.y);
      pk[6] = (short)f2bf(a1.z); pk[7] = (short)f2bf(a1.w);
      *(short8*)&As[row][sc] = pk;
      *(float4*)&Bs[row][sc] = *(const float4*)(Bt + (bn + row) * (size_t)K + k0 + sc);
    }
    __syncthreads();
    short8 af[4], bf[4];
#pragma unroll
    for (int mi = 0; mi < 4; ++mi) af[mi] = *(const short8*)&As[wrow + mi * 16 + lr][quad * 8];
#pragma unroll
    for (int ni = 0; ni < 4; ++ni) bf[ni] = *(const short8*)&Bs[wcol + ni * 16 + lr][quad * 8];
#pragma unroll
    for (int mi = 0; mi < 4; ++mi)
#pragma unroll
      for (int ni = 0; ni < 4; ++ni)
        acc[mi][ni] = __builtin_amdgcn_mfma_f32_16x16x32_bf16(af[mi], bf[ni], acc[mi][ni], 0, 0, 0);
    __syncthreads();
  }

  float* outf = (float*)Cout;
  unsigned short* outb = (unsigned short*)Cout;
#pragma unroll
  for (int mi = 0; mi < 4; ++mi) {
#pragma unroll
    for (int ni = 0; ni < 4; ++ni) {
      const size_t row0 = bm + wrow + mi * 16 + quad * 4;
      const size_t col  = bn + wcol + ni * 16 + lr;
      const float bsum = bias ? bias[col] : 0.f;
      if (out_mode == 2) {
        // imgW8 layout: [b][j][col][i], b=row/64, j=(row%64)>>3, i=(row%64)&7
        const size_t bidx = row0 >> 6;
        const int l0 = (int)(row0 & 63);
        const int j = l0 >> 3, i0 = l0 & 7;      // i0 in {0,4}: 4 regs contiguous
        ushort4v pk;
#pragma unroll
        for (int reg = 0; reg < 4; ++reg) pk[reg] = f2bf(acc[mi][ni][reg] + bsum);
        *(ushort4v*)(outb + (((bidx * 8 + j) * 1536 + col) << 3) + i0) = pk;
      } else {
#pragma unroll
        for (int reg = 0; reg < 4; ++reg) {
          const float v = acc[mi][ni][reg] + bsum;
          if (out_mode == 1) outb[(row0 + reg) * (size_t)N + col] = f2bf(v);
          else               outf[(row0 + reg) * (size_t)N + col] = v;
        }
      }
    }
  }
}

// ---------------------------------------------------------------------------
// small helpers
// ---------------------------------------------------------------------------
// in[K,N] fp32 -> out[N,K] bf16 (tiled transpose). K%32==0, N%32==0.
__global__ __launch_bounds__(256) void transpose_f32_bf16(
    const float* __restrict__ in, unsigned short* __restrict__ outp, int K, int N) {
  __shared__ unsigned short tile[32][33];
  const int tid = threadIdx.x;
  const int tx = tid & 31, ty = tid >> 5;  // ty 0..7
  const int k0 = blockIdx.y * 32, n0 = blockIdx.x * 32;
#pragma unroll
  for (int i = 0; i < 4; ++i) {
    const int kk = ty + i * 8;
    tile[tx][kk] = f2bf(in[(size_t)(k0 + kk) * N + n0 + tx]);
  }
  __syncthreads();
#pragma unroll
  for (int i = 0; i < 4; ++i) {
    const int nn = ty + i * 8;
    outp[(size_t)(n0 + nn) * K + k0 + tx] = tile[nn][tx];
  }
}

// bcat[2048] = [att_hid_bias | rec_bias]
__global__ void build_bcat(const float* __restrict__ ahb,
                           const float* __restrict__ rb,
                           float* __restrict__ bcat) {
  int i = blockIdx.x * 256 + threadIdx.x;
  if (i < A_) bcat[i] = ahb[i];
  else if (i < A_ + N3U) bcat[i] = rb[i - A_];
}

// Wcat8[k8][n][i] = W[k8*8+i][n] bf16, W = [att_hid_k | rec_kern] columns n=0..2047.
// Thread-per-n, coalesced 16B stores; GEMV reads 16B/lane at consecutive n.
__global__ __launch_bounds__(256) void build_wcat8(
    const float* __restrict__ ahk,   // [512,512]
    const float* __restrict__ rk,    // [512,1536]
    unsigned short* __restrict__ w8) {
  const int n  = blockIdx.x * 256 + threadIdx.x;  // 0..2047
  const int k8 = blockIdx.y;                       // 0..63
  short8 pk;
#pragma unroll
  for (int i = 0; i < 8; ++i) {
    const int k = k8 * 8 + i;
    const float v = (n < 512) ? ahk[(size_t)k * 512 + n]
                              : rk[(size_t)k * 1536 + (n - 512)];
    pk[i] = (short)f2bf(v);
  }
  *(short8*)(w8 + ((size_t)(k8 * 2048 + n)) * 8) = pk;
}

// ---------------------------------------------------------------------------
// Batch-parallel persistent recurrence: block b owns batch b for all 32 steps.
// No cross-block dependency exists (hm[b], attention[b], h[b] are all local),
// so this is a PLAIN launch: no grid.sync, no per-step kernel launches.
// h and hm live in LDS for the whole kernel.
// Per step:
//   phase 0: hm = h @ Wcat + bcat   (per-block GEMV, K=512, N=2048;
//            Wcat8 reads 16B/lane coalesced; Wcat is L2-resident per XCD)
//   phase A: scores over 64 regions (wave w -> l = w, w+8, ...)
//   softmax (first 64 threads)
//   phase B: combine via imgW8 (24 coalesced 16B loads) + GRU gates
// ---------------------------------------------------------------------------
__global__ __launch_bounds__(512) void recurrence_bp(
    const unsigned short* __restrict__ img_proj,   // [B,L,A] bf16
    const unsigned short* __restrict__ imgW8,      // [B][8][3U][8] bf16
    const float* __restrict__ text_proj,           // [B,T,3U] fp32
    const unsigned short* __restrict__ wcat8,      // [64][2048][8] bf16
    const float* __restrict__ bcat,                // [2048]
    const float* __restrict__ vk,                  // [A]
    float* __restrict__ out) {                     // [B,T,U]
  const int b    = blockIdx.x;
  const int tid  = threadIdx.x;
  const int lane = tid & 63;
  const int wave = tid >> 6;   // 0..7

  __shared__ float h_s[U_];      // hidden state, fp32
  __shared__ float hm_s[2048];   // [hproj | mi]
  __shared__ float sc[L_];
  __shared__ float aw[L_];

  h_s[tid] = 0.f;

  // hoisted invariants
  float vvv[8];
  {
    float4 v0 = *(const float4*)(vk + lane * 8);
    float4 v1 = *(const float4*)(vk + lane * 8 + 4);
    vvv[0]=v0.x; vvv[1]=v0.y; vvv[2]=v0.z; vvv[3]=v0.w;
    vvv[4]=v1.x; vvv[5]=v1.y; vvv[6]=v1.z; vvv[7]=v1.w;
  }
  float bcv[4];
#pragma unroll
  for (int j = 0; j < 4; ++j) bcv[j] = bcat[tid + 512 * j];

  __syncthreads();

  for (int t = 0; t < T_; ++t) {
    // ---- phase 0: GEMV hm = h @ Wcat + bcat; thread owns n = tid + 512j ----
    {
      float a0 = 0.f, a1 = 0.f, a2 = 0.f, a3 = 0.f;
      const unsigned short* wp = wcat8 + (size_t)tid * 8;
#pragma unroll 2
      for (int k8 = 0; k8 < 64; ++k8) {
        float4 h0 = *(const float4*)&h_s[k8 * 8];
        float4 h1 = *(const float4*)&h_s[k8 * 8 + 4];
        const unsigned short* wk = wp + (size_t)k8 * (2048 * 8);
        short8 w0 = *(const short8*)(wk);
        short8 w1 = *(const short8*)(wk + 512 * 8);
        short8 w2 = *(const short8*)(wk + 1024 * 8);
        short8 w3 = *(const short8*)(wk + 1536 * 8);
#define DOT8(ACC, W)                                                   \
        ACC += bf2f((unsigned short)W[0]) * h0.x;                      \
        ACC += bf2f((unsigned short)W[1]) * h0.y;                      \
        ACC += bf2f((unsigned short)W[2]) * h0.z;                      \
        ACC += bf2f((unsigned short)W[3]) * h0.w;                      \
        ACC += bf2f((unsigned short)W[4]) * h1.x;                      \
        ACC += bf2f((unsigned short)W[5]) * h1.y;                      \
        ACC += bf2f((unsigned short)W[6]) * h1.z;                      \
        ACC += bf2f((unsigned short)W[7]) * h1.w;
        DOT8(a0, w0) DOT8(a1, w1) DOT8(a2, w2) DOT8(a3, w3)
#undef DOT8
      }
      hm_s[tid]        = a0 + bcv[0];
      hm_s[tid + 512]  = a1 + bcv[1];
      hm_s[tid + 1024] = a2 + bcv[2];
      hm_s[tid + 1536] = a3 + bcv[3];
    }
    __syncthreads();

    // ---- phase A: attention scores ----
    float hpv[8];
    {
      float4 h0 = *(const float4*)&hm_s[lane * 8];
      float4 h1 = *(const float4*)&hm_s[lane * 8 + 4];
      hpv[0]=h0.x; hpv[1]=h0.y; hpv[2]=h0.z; hpv[3]=h0.w;
      hpv[4]=h1.x; hpv[5]=h1.y; hpv[6]=h1.z; hpv[7]=h1.w;
    }
#pragma unroll
    for (int i = 0; i < 8; ++i) {
      const int l = wave + i * 8;
      const unsigned short* ip = img_proj + ((size_t)b * L_ + l) * A_ + lane * 8;
      short8 v8 = *(const short8*)ip;
      float s = 0.f;
#pragma unroll
      for (int j = 0; j < 8; ++j)
        s += fast_tanh(bf2f((unsigned short)v8[j]) + hpv[j]) * vvv[j];
#pragma unroll
      for (int off = 32; off; off >>= 1) s += __shfl_down(s, off);
      if (lane == 0) sc[l] = s;
    }
    __syncthreads();

    // softmax over 64 regions
    if (tid < 64) {
      float x = sc[tid];
      float m = x;
#pragma unroll
      for (int off = 32; off; off >>= 1) m = fmaxf(m, __shfl_xor(m, off));
      float e = __expf(x - m);
      float ssum = e;
#pragma unroll
      for (int off = 32; off; off >>= 1) ssum += __shfl_xor(ssum, off);
      aw[tid] = e / ssum;
    }
    __syncthreads();

    // ---- phase B: combine + GRU; thread u owns gate triple (u,512+u,1024+u) ----
    const int u = tid;
    const unsigned short* iwb = imgW8 + (size_t)b * 8 * (N3U * 8) + (size_t)u * 8;
    float s0 = 0.f, s1 = 0.f, s2 = 0.f;
#pragma unroll
    for (int j = 0; j < 8; ++j) {
      const unsigned short* pj = iwb + (size_t)j * (N3U * 8);
      short8 v0 = *(const short8*)(pj);
      short8 v1 = *(const short8*)(pj + 512 * 8);
      short8 v2 = *(const short8*)(pj + 1024 * 8);
#pragma unroll
      for (int i = 0; i < 8; ++i) {
        const float a = aw[j * 8 + i];      // l = j*8+i: same order as before
        s0 += a * bf2f((unsigned short)v0[i]);
        s1 += a * bf2f((unsigned short)v1[i]);
        s2 += a * bf2f((unsigned short)v2[i]);
      }
    }
    const float* tp = text_proj + ((size_t)b * T_ + t) * N3U;
    const float xz = s0 + tp[u]        + hm_s[512 + u];
    const float xr = s1 + tp[512 + u]  + hm_s[1024 + u];
    const float xh = s2 + tp[1024 + u];
    const float rh = hm_s[1536 + u];
    const float z  = 1.f / (1.f + __expf(-xz));
    const float r  = 1.f / (1.f + __expf(-xr));
    const float hh = fast_tanh(xh + r * rh);
    const float hn = z * h_s[u] + (1.f - z) * hh;
    out[((size_t)b * T_ + t) * U_ + u] = hn;
    h_s[u] = hn;          // own element only; next GEMV reads after sync
    __syncthreads();
  }
}

// ---------------------------------------------------------------------------
// launch
// ---------------------------------------------------------------------------
extern "C" void kernel_launch(void* const* d_in, const int* in_sizes, int n_in,
                              void* d_out, int out_size, void* d_ws, size_t ws_size,
                              hipStream_t stream) {
  const float* img        = (const float*)d_in[0];   // [B,L,DI]
  const float* text       = (const float*)d_in[1];   // [B,T,DT]
  const float* kern       = (const float*)d_in[2];   // [DT+DI, 3U]
  const float* input_bias = (const float*)d_in[3];   // [3U]
  const float* rec_kern   = (const float*)d_in[4];   // [U,3U]
  const float* rec_bias   = (const float*)d_in[5];   // [3U]
  const float* att_img_k  = (const float*)d_in[6];   // [DI,A]
  const float* att_img_b  = (const float*)d_in[7];   // [A]
  const float* att_hid_k  = (const float*)d_in[8];   // [U,A]
  const float* att_hid_b  = (const float*)d_in[9];   // [A]
  const float* att_v_k    = (const float*)d_in[10];  // [A,1]
  // d_in[11] = att_v_bias — cancels in softmax.
  float* out = (float*)d_out;

  // workspace layout (bytes, 256-aligned). NO ALIASING.
  char* ws = (char*)d_ws;
  size_t off = 0;
  auto alloc = [&](size_t bytes) { char* p = ws + off; off += (bytes + 255) & ~(size_t)255; return p; };
  unsigned short* img_proj = (unsigned short*)alloc((size_t)B_*L_*A_*2);   // 16.8 MB bf16
  unsigned short* imgW8    = (unsigned short*)alloc((size_t)B_*L_*N3U*2);  // 50.3 MB bf16 [b][j][n][i]
  float*          text_proj= (float*)         alloc((size_t)B_*T_*N3U*4);  // 50.3 MB fp32
  unsigned short* wt1      = (unsigned short*)alloc((size_t)A_*DI_*2);     // att_img_k^T
  unsigned short* wt2      = (unsigned short*)alloc((size_t)N3U*DI_*2);    // kern[DT:]^T
  unsigned short* wt3      = (unsigned short*)alloc((size_t)N3U*DT_*2);    // kern[:DT]^T
  unsigned short* wcat8    = (unsigned short*)alloc((size_t)64*2048*8*2);  // 2 MB bf16
  float*          bcat     = (float*)         alloc(2048*4);

  dim3 blk(256);

  // one-time weight transforms
  transpose_f32_bf16<<<dim3(A_/32, DI_/32), blk, 0, stream>>>(att_img_k, wt1, DI_, A_);
  transpose_f32_bf16<<<dim3(N3U/32, DI_/32), blk, 0, stream>>>(kern + (size_t)DT_*N3U, wt2, DI_, N3U);
  transpose_f32_bf16<<<dim3(N3U/32, DT_/32), blk, 0, stream>>>(kern, wt3, DT_, N3U);
  build_wcat8<<<dim3(2048/256, 64), blk, 0, stream>>>(att_hid_k, rec_kern, wcat8);
  build_bcat<<<dim3(8), blk, 0, stream>>>(att_hid_b, rec_bias, bcat);

  // big GEMMs on MFMA (A operand converted fp32->bf16 during staging)
  gemm_a32_bt16_mfma<<<dim3(A_/128, (B_*L_)/128), blk, 0, stream>>>(
      img, wt1, att_img_b, img_proj, B_*L_, A_, DI_, 1);
  gemm_a32_bt16_mfma<<<dim3(N3U/128, (B_*L_)/128), blk, 0, stream>>>(
      img, wt2, nullptr, imgW8, B_*L_, N3U, DI_, 2);     // direct imgW8 layout
  gemm_a32_bt16_mfma<<<dim3(N3U/128, (B_*T_)/128), blk, 0, stream>>>(
      text, wt3, input_bias, text_proj, B_*T_, N3U, DT_, 0);

  // entire 32-step recurrence: ONE plain launch, block b = batch b, no syncs
  recurrence_bp<<<dim3(B_), dim3(512), 0, stream>>>(
      img_proj, imgW8, text_proj, wcat8, bcat, att_v_k, out);
}